// Round 1
// 299.729 us; speedup vs baseline: 1.0541x; 1.0541x over previous
//
#include <hip/hip_runtime.h>
#include <hip/hip_bf16.h>

typedef __bf16 bf16x8 __attribute__((ext_vector_type(8)));
typedef __bf16 bf16x4 __attribute__((ext_vector_type(4)));
typedef float  f32x4  __attribute__((ext_vector_type(4)));

#define LAYERS 16
#define DIM 64
#define NHID 256
#define BATCH 32768
#define MTILE 64
#define NBLOCKS (BATCH / MTILE)   // 512

// packed weight sizes in bf16 elements
#define W0P_PER 16384             // per (net,layer): 16 otiles * 2 ktiles * 512
#define W1P_PER 65536             // 16 otiles * 8 ktiles * 512
#define W2P_PER 16384             // 4 otiles * 8 ktiles * 512
#define W0P_TOT (32 * W0P_PER)    // 524288
#define W1P_TOT (32 * W1P_PER)    // 2097152
#define W2P_TOT (32 * W2P_PER)    // 524288
#define PACK_TOT (W0P_TOT + W1P_TOT + W2P_TOT)  // 3145728 bf16 = 6.29 MB

__device__ __forceinline__ bf16x8 ldw(const __bf16* p) { return *(const bf16x8*)p; }

// ---------------------------------------------------------------------------
// Pack kernel (unchanged from round 7): analytic masks, fragment-order output.
// ---------------------------------------------------------------------------
__global__ __launch_bounds__(256) void pack_weights(
    const float* __restrict__ lW0, const float* __restrict__ lW1, const float* __restrict__ lW2,
    const float* __restrict__ sW0, const float* __restrict__ sW1, const float* __restrict__ sW2,
    __bf16* __restrict__ ws)
{
    const long i = ((long)blockIdx.x * 256 + threadIdx.x) * 8;  // elem base
    const float* W; long src; int l, n, k, which;
    if (i < W0P_TOT) {
        int netl = (int)(i / W0P_PER), rem = (int)(i % W0P_PER);
        int net = netl >> 4; l = netl & 15;
        int nt = rem >> 10, kt = (rem >> 9) & 1, lane = (rem >> 3) & 63;
        n = nt * 16 + (lane & 15); k = kt * 32 + (lane >> 4) * 8;
        W = net ? sW0 : lW0; which = 0;
        src = (long)(l * 256 + n) * 64 + k;
    } else if (i < W0P_TOT + W1P_TOT) {
        long r = i - W0P_TOT;
        int netl = (int)(r / W1P_PER), rem = (int)(r % W1P_PER);
        int net = netl >> 4; l = netl & 15;
        int nt = rem >> 12, kt = (rem >> 9) & 7, lane = (rem >> 3) & 63;
        n = nt * 16 + (lane & 15); k = kt * 32 + (lane >> 4) * 8;
        W = net ? sW1 : lW1; which = 1;
        src = (long)(l * 256 + n) * 256 + k;
    } else {
        long r = i - W0P_TOT - W1P_TOT;
        int netl = (int)(r / W2P_PER), rem = (int)(r % W2P_PER);
        int net = netl >> 4; l = netl & 15;
        int nt = rem >> 12, kt = (rem >> 9) & 7, lane = (rem >> 3) & 63;
        n = nt * 16 + (lane & 15); k = kt * 32 + (lane >> 4) * 8;
        W = net ? sW2 : lW2; which = 2;
        src = (long)(l * 64 + n) * 256 + k;
    }
    f32x4 wa = *(const f32x4*)(W + src);
    f32x4 wb = *(const f32x4*)(W + src + 4);
    const int nm = n % 63;                   // mh(n) for which 0/1
    const int pn = (l & 1) ? 63 - n : n;     // perm(n) for which 2 (n < 64 there)
    bf16x8 o;
    #pragma unroll
    for (int j = 0; j < 8; ++j) {
        int kk = k + j;
        bool m;
        if (which == 0)      { int pk = (l & 1) ? 63 - kk : kk; m = (pk <= nm); }
        else if (which == 1) { m = ((kk % 63) <= nm); }
        else                 { m = ((kk % 63) < pn); }
        float v = (j < 4) ? wa[j] : wb[j - 4];
        o[j] = m ? (__bf16)v : (__bf16)0.0f;
    }
    *(bf16x8*)(ws + i) = o;
}

// ---------------------------------------------------------------------------
// Flow kernel, round 8: OCCUPANCY. Same algorithm / LDS (72 KB) / fragment
// layouts as r7, but 512 threads = 8 waves per block. 72 KB still gives
// 2 blocks/CU, so waves/CU goes 8 -> 16 (2 -> 4 per SIMD): barrier and
// epilogue stalls of one wave are covered by 3 other resident waves instead
// of 1. Work split: G1/G2 each wave owns otiles {2w, 2w+1}; G3 wave owns
// (dim tile otD = w>>1, batch half bh = w&1) so the coupling update stays in
// registers. y regs: y[bt][r] = row (blk*64 + bh*32 + bt*16 + l16),
// dim (otD*16 + quad*4 + r). Per-wave acc/prefetch halve -> VGPR <= 128 for
// __launch_bounds__(512,4). W2 tiles loaded by wave pairs (2x, +32KB/layer/
// block on L2 - negligible). Barrier ordering identical to r7 (B1/B2/B3 per
// net; buf lifetimes unchanged).
// ---------------------------------------------------------------------------
__global__ void __launch_bounds__(512, 4)
flow_kernel(
    const float* __restrict__ u,
    const __bf16* __restrict__ wp,
    const float* __restrict__ lb0, const float* __restrict__ lb1, const float* __restrict__ lb2,
    const float* __restrict__ sb0, const float* __restrict__ sb1, const float* __restrict__ sb2,
    float* __restrict__ out)
{
    __shared__ __bf16 ybf[4 * 2 * 512];     // [bt][kt(2)][lane][8]   8 KB
    __shared__ __bf16 buf1[4 * 8 * 512];    // [bt][kt(8)][lane][8]  32 KB
    __shared__ __bf16 buf2[4 * 8 * 512];    //                       32 KB

    const int tid  = threadIdx.x;
    const int w    = tid >> 6;        // 0..7
    const int lane = tid & 63;
    const int quad = lane >> 4;
    const int l16  = lane & 15;
    const int blk  = blockIdx.x;

    const int qh = quad >> 1;
    const int qp = (quad & 1) * 4;

    const int otD = w >> 1;           // G3 dim tile (0..3); y dim slice
    const int bh  = w & 1;            // G3 batch half; y batch half

    const __bf16* w0p = wp;
    const __bf16* w1p = wp + W0P_TOT;
    const __bf16* w2p = wp + W0P_TOT + W1P_TOT;

    // y regs: y[bt][r] = row (blk*64 + bh*32 + bt*16 + l16), dim (otD*16 + quad*4 + r)
    f32x4 y[2];
    #pragma unroll
    for (int bt = 0; bt < 2; ++bt)
        y[bt] = *(const f32x4*)(u + (long)(blk * MTILE + bh * 32 + bt * 16 + l16) * DIM
                                  + otD * 16 + quad * 4);

    // y-staging fragment coords: dim D = otD*16 + quad*4 + r ->
    // ktY = D/32 = w>>2, frag-lane = l16 + 16*(((w>>1)&1)*2 + qh), j = qp + r
    const int ktY = w >> 2;
    const int flY = ((((w >> 1) & 1) * 2 + qh) * 16 + l16);

    // prime: G1 weights for (net0, layer0) — wave's otiles are {2w, 2w+1}
    bf16x8 wg1[4];   // [oi][kt]
    #pragma unroll
    for (int oi = 0; oi < 2; ++oi)
        #pragma unroll
        for (int kt = 0; kt < 2; ++kt)
            wg1[oi * 2 + kt] = ldw(w0p + (long)((2 * w + oi) * 2 + kt) * 512 + lane * 8);

    for (int l = 0; l < LAYERS; ++l) {
        // stage y -> bf16 B-fragments (one b64 write per bt)
        #pragma unroll
        for (int bt = 0; bt < 2; ++bt) {
            bf16x4 v;
            #pragma unroll
            for (int r = 0; r < 4; ++r) v[r] = (__bf16)y[bt][r];
            *(bf16x4*)&ybf[(((bh * 2 + bt) * 2 + ktY) * 64 + flY) * 8 + qp] = v;
        }
        __syncthreads();  // B1: ybf ready

        f32x4 locr[2], scr[2];

        #pragma unroll
        for (int net = 0; net < 2; ++net) {
            const __bf16* w1b = w1p + (long)(net * 16 + l) * W1P_PER;
            const __bf16* w2b = w2p + (long)(net * 16 + l) * W2P_PER;
            // next G1 slot: net0 -> (net1, l); net1 -> (net0, l+1). l=15/net1
            // lands on slot 16 (net1, l0): in-bounds, values unused.
            const __bf16* w0n = w0p + (long)(net == 0 ? 16 + l : l + 1) * W0P_PER;
            const float* b0 = (net ? sb0 : lb0) + l * 256;
            const float* b1 = (net ? sb1 : lb1) + l * 256;
            const float* b2 = (net ? sb2 : lb2) + l * 64;

            bf16x8 wg2a[8];  // G2 weights kt 0..3 x oi 0..1

            // ---- G1: W0 (A, prefetched in wg1) x y^T (B, fragments) -> h0 frags
            {
                f32x4 acc[2][4];
                #pragma unroll
                for (int oi = 0; oi < 2; ++oi)
                    #pragma unroll
                    for (int bt = 0; bt < 4; ++bt)
                        acc[oi][bt] = (f32x4){0.f, 0.f, 0.f, 0.f};
                #pragma unroll
                for (int kt = 0; kt < 2; ++kt) {
                    bf16x8 bv[4];
                    #pragma unroll
                    for (int bt = 0; bt < 4; ++bt)
                        bv[bt] = *(const bf16x8*)&ybf[((bt * 2 + kt) * 64 + lane) * 8];
                    #pragma unroll
                    for (int oi = 0; oi < 2; ++oi)
                        #pragma unroll
                        for (int bt = 0; bt < 4; ++bt)
                            acc[oi][bt] = __builtin_amdgcn_mfma_f32_16x16x32_bf16(wg1[oi * 2 + kt], bv[bt], acc[oi][bt], 0, 0, 0);
                }
                // prefetch G2 kt=0..3 across the upcoming barrier
                #pragma unroll
                for (int kt = 0; kt < 4; ++kt)
                    #pragma unroll
                    for (int oi = 0; oi < 2; ++oi)
                        wg2a[kt * 2 + oi] = ldw(w1b + (long)((2 * w + oi) * 8 + kt) * 512 + lane * 8);
                // epilogue: relu + bias -> buf1 fragments
                // hidden h = (2w+oi)*16 + quad*4 + r -> kt1 = h/32 = w,
                // frag-lane = l16 + 16*(oi*2+qh), j = qp + r
                #pragma unroll
                for (int oi = 0; oi < 2; ++oi) {
                    f32x4 bias = *(const f32x4*)(b0 + (2 * w + oi) * 16 + quad * 4);
                    const int fl = ((oi * 2 + qh) * 16 + l16);
                    #pragma unroll
                    for (int bt = 0; bt < 4; ++bt) {
                        bf16x4 v;
                        #pragma unroll
                        for (int r = 0; r < 4; ++r)
                            v[r] = (__bf16)fmaxf(acc[oi][bt][r] + bias[r], 0.f);
                        *(bf16x4*)&buf1[((bt * 8 + w) * 64 + fl) * 8 + qp] = v;
                    }
                }
            }
            __syncthreads();  // B2: h0 ready

            bf16x8 wg3[8];    // G3 weights [kt]

            // ---- G2: W1 (A, kt<4 prefetched) x h0 (B, fragments) -> h1 frags
            {
                f32x4 acc[2][4];
                #pragma unroll
                for (int oi = 0; oi < 2; ++oi)
                    #pragma unroll
                    for (int bt = 0; bt < 4; ++bt)
                        acc[oi][bt] = (f32x4){0.f, 0.f, 0.f, 0.f};
                #pragma unroll
                for (int kt = 0; kt < 8; ++kt) {
                    bf16x8 aw[2];
                    #pragma unroll
                    for (int oi = 0; oi < 2; ++oi)
                        aw[oi] = (kt < 4) ? wg2a[kt * 2 + oi]
                                          : ldw(w1b + (long)((2 * w + oi) * 8 + kt) * 512 + lane * 8);
                    bf16x8 bv[4];
                    #pragma unroll
                    for (int bt = 0; bt < 4; ++bt)
                        bv[bt] = *(const bf16x8*)&buf1[((bt * 8 + kt) * 64 + lane) * 8];
                    #pragma unroll
                    for (int oi = 0; oi < 2; ++oi)
                        #pragma unroll
                        for (int bt = 0; bt < 4; ++bt)
                            acc[oi][bt] = __builtin_amdgcn_mfma_f32_16x16x32_bf16(aw[oi], bv[bt], acc[oi][bt], 0, 0, 0);
                }
                // epilogue: relu + bias -> buf2 fragments
                #pragma unroll
                for (int oi = 0; oi < 2; ++oi) {
                    f32x4 bias = *(const f32x4*)(b1 + (2 * w + oi) * 16 + quad * 4);
                    const int fl = ((oi * 2 + qh) * 16 + l16);
                    #pragma unroll
                    for (int bt = 0; bt < 4; ++bt) {
                        bf16x4 v;
                        #pragma unroll
                        for (int r = 0; r < 4; ++r)
                            v[r] = (__bf16)fmaxf(acc[oi][bt][r] + bias[r], 0.f);
                        *(bf16x4*)&buf2[((bt * 8 + w) * 64 + fl) * 8 + qp] = v;
                    }
                }
                // prefetch G3 weights across the upcoming barrier (wave pair
                // w, w^1 load the same otD tile — 2x W2 loads, negligible)
                #pragma unroll
                for (int kt = 0; kt < 8; ++kt)
                    wg3[kt] = ldw(w2b + (long)(otD * 8 + kt) * 512 + lane * 8);
            }
            __syncthreads();  // B3: h1 ready (also all buf1 reads done)

            // ---- G3: W2 (A, prefetched in wg3) x h1 (B, fragments) -> regs
            // wave owns (dim tile otD, batch half bh): bt in {bh*2, bh*2+1}
            {
                f32x4 acc3[2];
                #pragma unroll
                for (int bt = 0; bt < 2; ++bt)
                    acc3[bt] = (f32x4){0.f, 0.f, 0.f, 0.f};
                #pragma unroll
                for (int kt = 0; kt < 8; ++kt) {
                    #pragma unroll
                    for (int bt = 0; bt < 2; ++bt) {
                        bf16x8 bv = *(const bf16x8*)&buf2[(((bh * 2 + bt) * 8 + kt) * 64 + lane) * 8];
                        acc3[bt] = __builtin_amdgcn_mfma_f32_16x16x32_bf16(wg3[kt], bv, acc3[bt], 0, 0, 0);
                    }
                }
                // prefetch next G1 weights (low-pressure region)
                #pragma unroll
                for (int oi = 0; oi < 2; ++oi)
                    #pragma unroll
                    for (int kt = 0; kt < 2; ++kt)
                        wg1[oi * 2 + kt] = ldw(w0n + (long)((2 * w + oi) * 2 + kt) * 512 + lane * 8);
                f32x4 bias = *(const f32x4*)(b2 + otD * 16 + quad * 4);
                if (net == 0) {
                    #pragma unroll
                    for (int bt = 0; bt < 2; ++bt)
                        #pragma unroll
                        for (int r = 0; r < 4; ++r)
                            locr[bt][r] = acc3[bt][r] + bias[r];
                } else {
                    #pragma unroll
                    for (int bt = 0; bt < 2; ++bt)
                        #pragma unroll
                        for (int r = 0; r < 4; ++r)
                            scr[bt][r] = acc3[bt][r] + bias[r];
                }
            }
            // no barrier after G3: next G1 writes buf1 (reads drained at B3);
            // next G2's buf2 writes are behind the next B2
        }

        // coupling update, pure registers: y = exp(-sc) * (y - loc)
        #pragma unroll
        for (int bt = 0; bt < 2; ++bt)
            #pragma unroll
            for (int r = 0; r < 4; ++r)
                y[bt][r] = __expf(-scr[bt][r]) * (y[bt][r] - locr[bt][r]);
        // next ybf write safe: all ybf readers (both nets' G1) are behind this
        // layer's B2 barriers
    }

    #pragma unroll
    for (int bt = 0; bt < 2; ++bt)
        *(f32x4*)(out + (long)(blk * MTILE + bh * 32 + bt * 16 + l16) * DIM
                      + otD * 16 + quad * 4) = y[bt];
}

extern "C" void kernel_launch(void* const* d_in, const int* in_sizes, int n_in,
                              void* d_out, int out_size, void* d_ws, size_t ws_size,
                              hipStream_t stream) {
    const float* u   = (const float*)d_in[0];
    const float* lW0 = (const float*)d_in[1];
    const float* lb0 = (const float*)d_in[2];
    const float* lW1 = (const float*)d_in[3];
    const float* lb1 = (const float*)d_in[4];
    const float* lW2 = (const float*)d_in[5];
    const float* lb2 = (const float*)d_in[6];
    const float* sW0 = (const float*)d_in[7];
    const float* sb0 = (const float*)d_in[8];
    const float* sW1 = (const float*)d_in[9];
    const float* sb1 = (const float*)d_in[10];
    const float* sW2 = (const float*)d_in[11];
    const float* sb2 = (const float*)d_in[12];
    // d_in[13..15] = M0,M1,M2 — masks are computed analytically in pack_weights

    if (ws_size < (size_t)PACK_TOT * sizeof(__bf16)) return;
    __bf16* ws = (__bf16*)d_ws;

    pack_weights<<<PACK_TOT / 8 / 256, 256, 0, stream>>>(
        lW0, lW1, lW2, sW0, sW1, sW2, ws);
    flow_kernel<<<NBLOCKS, 512, 0, stream>>>(
        u, ws, lb0, lb1, lb2, sb0, sb1, sb2, (float*)d_out);
}